// Round 1
// baseline (775.713 us; speedup 1.0000x reference)
//
#include <hip/hip_runtime.h>
#include <math.h>

// ---------------------------------------------------------------------------
// MemoryRetriever: B=8, S=2048 (N=16384 rows), H=1024, M=256, NH=4, HD=64,
// NM=4096, K_SEL=512. fp32 I/O, bf16 MFMA internals (2%-of-max threshold).
// ---------------------------------------------------------------------------

typedef __bf16 bf16x8 __attribute__((ext_vector_type(8)));
typedef __bf16 bf16x4 __attribute__((ext_vector_type(4)));
typedef float  floatx4 __attribute__((ext_vector_type(4)));

#define N_ROWS 16384
#define HID    1024
#define MEMD   256
#define NMEM   4096
#define KSEL   512

// ---------------------------------------------------------------------------
// 1) fp32 -> bf16 conversion of qh + big weights (one pass, float4 chunks)
// ---------------------------------------------------------------------------
__global__ void cvt_kernel(const float* __restrict__ s0, const float* __restrict__ s1,
                           const float* __restrict__ s2, const float* __restrict__ s3,
                           const float* __restrict__ s4,
                           __bf16* __restrict__ d0, __bf16* __restrict__ d1,
                           __bf16* __restrict__ d2, __bf16* __restrict__ d3,
                           __bf16* __restrict__ d4) {
  long q = (long)blockIdx.x * 256 + threadIdx.x;  // quad index
  const long n0 = 16777216 / 4, n1 = 65536 / 4, n2 = 1310720 / 4,
             n3 = 2621440 / 4, n4 = 2097152 / 4;
  const float* s; __bf16* d; long off;
  if (q < n0) { s = s0; d = d0; off = q; }
  else if ((q -= n0) < n1) { s = s1; d = d1; off = q; }
  else if ((q -= n1) < n2) { s = s2; d = d2; off = q; }
  else if ((q -= n2) < n3) { s = s3; d = d3; off = q; }
  else if ((q -= n3) < n4) { s = s4; d = d4; off = q; }
  else return;
  float4 v = ((const float4*)s)[off];
  bf16x4 o;
  o[0] = (__bf16)v.x; o[1] = (__bf16)v.y; o[2] = (__bf16)v.z; o[3] = (__bf16)v.w;
  ((bf16x4*)d)[off] = o;
}

// ---------------------------------------------------------------------------
// 2) top-512 of 4096 scores: radix-select on order-mapped float bits.
//    Set semantics suffice (softmax over set is permutation invariant);
//    ties resolved to smallest indices to match lax.top_k.
// ---------------------------------------------------------------------------
__device__ __forceinline__ unsigned mapbits(float x) {
  unsigned b = __float_as_uint(x);
  return (b & 0x80000000u) ? ~b : (b | 0x80000000u);
}

__global__ void topk_kernel(const float* __restrict__ scores, int* __restrict__ idx_out) {
  const int n = NMEM, k = KSEL;
  __shared__ int hist[256];
  __shared__ int s_need;
  __shared__ unsigned s_prefix;
  __shared__ int s_cnt_gt, s_ntie;
  __shared__ int tie[1024];
  int tid = threadIdx.x;  // 256 threads
  if (tid == 0) { s_need = k; s_prefix = 0; s_cnt_gt = 0; s_ntie = 0; }
  __syncthreads();
  for (int pass = 0; pass < 4; ++pass) {
    if (tid < 256) hist[tid] = 0;
    __syncthreads();
    int shift = 24 - 8 * pass;
    unsigned pref = s_prefix;
    for (int i = tid; i < n; i += 256) {
      unsigned u = mapbits(scores[i]);
      bool in = (pass == 0) || ((u >> (shift + 8)) == pref);
      if (in) atomicAdd(&hist[(u >> shift) & 255], 1);
    }
    __syncthreads();
    if (tid == 0) {
      int need = s_need, above = 0, b = 255;
      for (;; --b) {
        int c = hist[b];
        if (above + c >= need) { s_need = need - above; break; }
        above += c;
      }
      s_prefix = (s_prefix << 8) | (unsigned)b;
    }
    __syncthreads();
  }
  unsigned T = s_prefix;
  int need = s_need;
  for (int i = tid; i < n; i += 256) {
    unsigned u = mapbits(scores[i]);
    if (u > T) { int p = atomicAdd(&s_cnt_gt, 1); idx_out[p] = i; }
    else if (u == T) { int t = atomicAdd(&s_ntie, 1); if (t < 1024) tie[t] = i; }
  }
  __syncthreads();
  int base = s_cnt_gt;
  int nt = s_ntie < 1024 ? s_ntie : 1024;
  for (int j = tid; j < nt; j += 256) {
    int my = tie[j], rank = 0;
    for (int l = 0; l < nt; ++l) rank += (tie[l] < my) ? 1 : 0;
    if (rank < need) idx_out[base + rank] = my;
  }
}

// ---------------------------------------------------------------------------
// 3) Wc = 0.125 * (wq @ qp_w)  [256 x 1024] bf16 ;  bcq = 0.125*(wq@qp_b + bq)
//    (q_emb folded into Q-projection; softmax 1/sqrt(64) folded in too)
// ---------------------------------------------------------------------------
__global__ void wc_build(const float* __restrict__ qp_w, const float* __restrict__ qp_b,
                         const float* __restrict__ in_w, const float* __restrict__ in_b,
                         __bf16* __restrict__ Wc, float* __restrict__ bcq) {
  int i = blockIdx.x, t = threadIdx.x;  // 256 blocks x 256 threads
  const float* wq = in_w + (long)i * 256;
  float a0 = 0, a1 = 0, a2 = 0, a3 = 0;
  for (int s = 0; s < 256; ++s) {
    float wv = wq[s];
    const float* qr = qp_w + (long)s * 1024 + t;
    a0 += wv * qr[0];   a1 += wv * qr[256];
    a2 += wv * qr[512]; a3 += wv * qr[768];
  }
  __bf16* wr = Wc + (long)i * 1024 + t;
  wr[0]   = (__bf16)(0.125f * a0); wr[256] = (__bf16)(0.125f * a1);
  wr[512] = (__bf16)(0.125f * a2); wr[768] = (__bf16)(0.125f * a3);
  if (t == 0) {
    float s = in_b[i];
    for (int j = 0; j < 256; ++j) s += wq[j] * qp_b[j];
    bcq[i] = 0.125f * s;
  }
}

// ---------------------------------------------------------------------------
// 4) gather + LN(ln1) + K / V projections.  K row-major [512,256] bf16;
//    V stored transposed: Vt[h][d][key] = [4][64][512] bf16 (so PV is X·W^T).
// ---------------------------------------------------------------------------
__global__ void kv_build(const int* __restrict__ idx, const float* __restrict__ mem_keys,
                         const float* __restrict__ in_w, const float* __restrict__ in_b,
                         const float* __restrict__ ln1g, const float* __restrict__ ln1b,
                         __bf16* __restrict__ Kmat, __bf16* __restrict__ Vt) {
  int r = blockIdx.x, t = threadIdx.x;  // 512 blocks x 256 threads
  __shared__ float red[256];
  __shared__ float m[256];
  int row = idx[r];
  float x = mem_keys[(long)row * 256 + t];
  red[t] = x; __syncthreads();
  for (int o = 128; o > 0; o >>= 1) { if (t < o) red[t] += red[t + o]; __syncthreads(); }
  float mu = red[0] / 256.0f; __syncthreads();
  float e = x - mu;
  red[t] = e * e; __syncthreads();
  for (int o = 128; o > 0; o >>= 1) { if (t < o) red[t] += red[t + o]; __syncthreads(); }
  float rstd = rsqrtf(red[0] / 256.0f + 1e-5f);
  m[t] = e * rstd * ln1g[t] + ln1b[t];
  __syncthreads();
  float ka = 0.f, va = 0.f;
  const float* wk = in_w + (long)(256 + t) * 256;
  const float* wv = in_w + (long)(512 + t) * 256;
  #pragma unroll 4
  for (int i = 0; i < 256; i += 4) {
    float4 wkv = *(const float4*)(wk + i);
    float4 wvv = *(const float4*)(wv + i);
    ka += m[i] * wkv.x + m[i + 1] * wkv.y + m[i + 2] * wkv.z + m[i + 3] * wkv.w;
    va += m[i] * wvv.x + m[i + 1] * wvv.y + m[i + 2] * wvv.z + m[i + 3] * wvv.w;
  }
  ka += in_b[256 + t]; va += in_b[512 + t];
  Kmat[(long)r * 256 + t] = (__bf16)ka;
  Vt[(long)(t >> 6) * (64 * 512) + (long)(t & 63) * 512 + r] = (__bf16)va;
}

// ---------------------------------------------------------------------------
// 5) Generic bf16 MFMA GEMM:  C[M x N] = epi( X[M x Ktot] · W[N x Ktot]^T + bias )
//    X optionally split in two segments along K (X1: K1 cols, X2: rest) so
//    cat=[qh, attn_out] is never materialized.  16x16x32 bf16 MFMA,
//    128-row tiles, BK=64, 4 waves in 2x2.  EPI: 0=bias, 1=none, 2=bias+sigmoid.
//    All M,N,K multiples of tile sizes by construction -> no bounds checks.
// ---------------------------------------------------------------------------
template <int BM, int BN, int EPI>
__launch_bounds__(256, 2)
__global__ void gemm_kernel(const __bf16* __restrict__ X1, int ldx1, int K1,
                            const __bf16* __restrict__ X2, int ldx2,
                            const __bf16* __restrict__ W, int ldw,
                            const float* __restrict__ bias,
                            __bf16* __restrict__ C, int ldc, int Ktot,
                            long sXz, long sWz, long sCz) {
  constexpr int BK = 64;
  constexpr int LDA = BK + 24;  // 88 shorts = 176B row stride: 16B-aligned, 2-way banks
  __shared__ __bf16 As[BM * LDA];
  __shared__ __bf16 Bs[BN * LDA];
  const int tid = threadIdx.x;
  const int lane = tid & 63, wave = tid >> 6;
  const int wm = wave >> 1, wn = wave & 1;
  constexpr int FM = (BM / 2) / 16, FN = (BN / 2) / 16;
  floatx4 acc[FM][FN];
  #pragma unroll
  for (int i = 0; i < FM; ++i)
    #pragma unroll
    for (int j = 0; j < FN; ++j)
      #pragma unroll
      for (int r = 0; r < 4; ++r) acc[i][j][r] = 0.0f;

  const long z = blockIdx.z;
  const __bf16* x1 = X1 + z * sXz;
  const __bf16* w  = W + z * sWz;
  __bf16* c = C + z * sCz;
  const long row0 = (long)blockIdx.x * BM;
  const int col0 = blockIdx.y * BN;
  const int nKt = Ktot / BK;

  for (int kt = 0; kt < nKt; ++kt) {
    const int k0 = kt * BK;
    #pragma unroll
    for (int i = 0; i < (BM * 8) / 256; ++i) {  // A tile: BM x 64 in 16B chunks
      int cidx = tid + i * 256;
      int row = cidx >> 3, cc = (cidx & 7) * 8;
      int kg = k0 + cc;
      const __bf16* src = (kg < K1) ? (x1 + (row0 + row) * (long)ldx1 + kg)
                                    : (X2 + (row0 + row) * (long)ldx2 + (kg - K1));
      bf16x8 v = *(const bf16x8*)src;
      *(bf16x8*)(As + row * LDA + cc) = v;
    }
    #pragma unroll
    for (int i = 0; i < (BN * 8) / 256; ++i) {  // B tile: BN x 64
      int cidx = tid + i * 256;
      int row = cidx >> 3, cc = (cidx & 7) * 8;
      bf16x8 v = *(const bf16x8*)(w + (long)(col0 + row) * ldw + (k0 + cc));
      *(bf16x8*)(Bs + row * LDA + cc) = v;
    }
    __syncthreads();
    #pragma unroll
    for (int kk = 0; kk < 2; ++kk) {
      bf16x8 a[FM], b[FN];
      const int koff = kk * 32 + (lane >> 4) * 8;
      #pragma unroll
      for (int fm = 0; fm < FM; ++fm)
        a[fm] = *(const bf16x8*)(As + (wm * (BM / 2) + fm * 16 + (lane & 15)) * LDA + koff);
      #pragma unroll
      for (int fn = 0; fn < FN; ++fn)
        b[fn] = *(const bf16x8*)(Bs + (wn * (BN / 2) + fn * 16 + (lane & 15)) * LDA + koff);
      #pragma unroll
      for (int fm = 0; fm < FM; ++fm)
        #pragma unroll
        for (int fn = 0; fn < FN; ++fn)
          acc[fm][fn] = __builtin_amdgcn_mfma_f32_16x16x32_bf16(a[fm], b[fn], acc[fm][fn], 0, 0, 0);
    }
    __syncthreads();
  }
  // epilogue: C/D layout col = lane&15, row = (lane>>4)*4 + r
  #pragma unroll
  for (int fn = 0; fn < FN; ++fn) {
    const int col = col0 + wn * (BN / 2) + fn * 16 + (lane & 15);
    float bv = (EPI == 1) ? 0.0f : bias[col];
    #pragma unroll
    for (int fm = 0; fm < FM; ++fm) {
      #pragma unroll
      for (int r = 0; r < 4; ++r) {
        long row = row0 + wm * (BM / 2) + fm * 16 + (lane >> 4) * 4 + r;
        float v = acc[fm][fn][r] + bv;
        if (EPI == 2) v = 1.0f / (1.0f + __expf(-v));
        c[row * (long)ldc + col] = (__bf16)v;
      }
    }
  }
}

// ---------------------------------------------------------------------------
// 6) softmax over 512 keys, in-place on bf16 S (one wave per row)
// ---------------------------------------------------------------------------
__global__ void softmax_kernel(__bf16* __restrict__ S) {
  long row = (long)blockIdx.x * 4 + (threadIdx.x >> 6);
  int lane = threadIdx.x & 63;
  __bf16* p = S + row * 512 + lane * 8;
  bf16x8 v = *(const bf16x8*)p;
  float f[8], mx = -1e30f;
  #pragma unroll
  for (int j = 0; j < 8; ++j) { f[j] = (float)v[j]; mx = fmaxf(mx, f[j]); }
  #pragma unroll
  for (int o = 32; o > 0; o >>= 1) mx = fmaxf(mx, __shfl_xor(mx, o));
  float s = 0.f;
  #pragma unroll
  for (int j = 0; j < 8; ++j) { f[j] = __expf(f[j] - mx); s += f[j]; }
  #pragma unroll
  for (int o = 32; o > 0; o >>= 1) s += __shfl_xor(s, o);
  float inv = 1.0f / s;
  bf16x8 o8;
  #pragma unroll
  for (int j = 0; j < 8; ++j) o8[j] = (__bf16)(f[j] * inv);
  *(bf16x8*)p = o8;
}

// ---------------------------------------------------------------------------
// 7) LN(int_ln) + exact gelu, in-place on t1 rows of 2048
// ---------------------------------------------------------------------------
__global__ void ln_gelu_kernel(__bf16* __restrict__ T1, const float* __restrict__ g,
                               const float* __restrict__ b) {
  long row = blockIdx.x; int t = threadIdx.x;  // 256 threads, 8 elems each
  __shared__ float red[256];
  __bf16* p = T1 + row * 2048 + t * 8;
  bf16x8 v = *(const bf16x8*)p;
  float f[8], s = 0.f;
  #pragma unroll
  for (int j = 0; j < 8; ++j) { f[j] = (float)v[j]; s += f[j]; }
  red[t] = s; __syncthreads();
  for (int o = 128; o > 0; o >>= 1) { if (t < o) red[t] += red[t + o]; __syncthreads(); }
  float mu = red[0] / 2048.0f; __syncthreads();
  s = 0.f;
  #pragma unroll
  for (int j = 0; j < 8; ++j) { f[j] -= mu; s += f[j] * f[j]; }
  red[t] = s; __syncthreads();
  for (int o = 128; o > 0; o >>= 1) { if (t < o) red[t] += red[t + o]; __syncthreads(); }
  float rstd = rsqrtf(red[0] / 2048.0f + 1e-5f);
  bf16x8 o8;
  #pragma unroll
  for (int j = 0; j < 8; ++j) {
    int cidx = t * 8 + j;
    float y = f[j] * rstd * g[cidx] + b[cidx];
    y = 0.5f * y * (1.0f + erff(y * 0.70710678118654752f));
    o8[j] = (__bf16)y;
  }
  *(bf16x8*)p = o8;
}

// ---------------------------------------------------------------------------
// 8) out = LN(qh + gate*integrated; ln2)  (fp32 out), rows of 1024
// ---------------------------------------------------------------------------
__global__ void final_kernel(const float* __restrict__ qh, const __bf16* __restrict__ gate,
                             const __bf16* __restrict__ integ, const float* __restrict__ g,
                             const float* __restrict__ b, float* __restrict__ out) {
  long row = blockIdx.x; int t = threadIdx.x;  // 256 threads, 4 elems each
  __shared__ float red[256];
  long base = row * 1024 + t * 4;
  float4 q = *(const float4*)(qh + base);
  bf16x4 gv = *(const bf16x4*)(gate + base);
  bf16x4 iv = *(const bf16x4*)(integ + base);
  float f[4] = { q.x + (float)gv[0] * (float)iv[0], q.y + (float)gv[1] * (float)iv[1],
                 q.z + (float)gv[2] * (float)iv[2], q.w + (float)gv[3] * (float)iv[3] };
  float s = f[0] + f[1] + f[2] + f[3];
  red[t] = s; __syncthreads();
  for (int o = 128; o > 0; o >>= 1) { if (t < o) red[t] += red[t + o]; __syncthreads(); }
  float mu = red[0] / 1024.0f; __syncthreads();
  s = 0.f;
  #pragma unroll
  for (int j = 0; j < 4; ++j) { f[j] -= mu; s += f[j] * f[j]; }
  red[t] = s; __syncthreads();
  for (int o = 128; o > 0; o >>= 1) { if (t < o) red[t] += red[t + o]; __syncthreads(); }
  float rstd = rsqrtf(red[0] / 1024.0f + 1e-5f);
  float4 ov;
  ov.x = f[0] * rstd * g[t * 4 + 0] + b[t * 4 + 0];
  ov.y = f[1] * rstd * g[t * 4 + 1] + b[t * 4 + 1];
  ov.z = f[2] * rstd * g[t * 4 + 2] + b[t * 4 + 2];
  ov.w = f[3] * rstd * g[t * 4 + 3] + b[t * 4 + 3];
  *(float4*)(out + base) = ov;
}

// ---------------------------------------------------------------------------
// launch
// ---------------------------------------------------------------------------
extern "C" void kernel_launch(void* const* d_in, const int* in_sizes, int n_in,
                              void* d_out, int out_size, void* d_ws, size_t ws_size,
                              hipStream_t stream) {
  const float* qh   = (const float*)d_in[0];
  const float* memk = (const float*)d_in[1];
  const float* sel  = (const float*)d_in[2];
  const float* qp_w = (const float*)d_in[3];
  const float* qp_b = (const float*)d_in[4];
  const float* inw  = (const float*)d_in[5];
  const float* inb  = (const float*)d_in[6];
  const float* outw = (const float*)d_in[7];
  const float* outb = (const float*)d_in[8];
  const float* gw   = (const float*)d_in[9];
  const float* gb   = (const float*)d_in[10];
  const float* w1   = (const float*)d_in[11];
  const float* b1   = (const float*)d_in[12];
  const float* lng  = (const float*)d_in[13];
  const float* lnb  = (const float*)d_in[14];
  const float* w2   = (const float*)d_in[15];
  const float* b2   = (const float*)d_in[16];
  const float* ln1g = (const float*)d_in[17];
  const float* ln1b = (const float*)d_in[18];
  const float* ln2g = (const float*)d_in[19];
  const float* ln2b = (const float*)d_in[20];
  float* out = (float*)d_out;
  char* ws = (char*)d_ws;

  // workspace arena (bytes); lifetimes: t1 overlays S/P, integ overlays qh_bf
  const size_t IDX_O   = 0;          // 512*4
  const size_t BCQ_O   = 2048;       // 256*4
  const size_t WCB_O   = 3072;       // 256*1024*2   = 524288
  const size_t KMAT_O  = 527360;     // 512*256*2    = 262144
  const size_t VT_O    = 789504;     // 4*64*512*2   = 262144
  const size_t OUTWB_O = 1051648;    // 65536*2      = 131072
  const size_t GATEW_O = 1182720;    // 1310720*2    = 2621440
  const size_t INTW1_O = 3804160;    // 2621440*2    = 5242880
  const size_t INTW2_O = 9047040;    // 2097152*2    = 4194304
  const size_t QHB_O   = 13241344;   // 16777216*2   = 33554432  (later: integrated)
  const size_t QB_O    = 46795776;   // 16384*256*2  = 8388608
  const size_t SB_O    = 55184384;   // 4*16384*512*2= 67108864  (later: t1)
  const size_t CTX_O   = 122293248;  // 8388608
  const size_t ATTN_O  = 130681856;  // 8388608
  const size_t GATE_O  = 139070464;  // 33554432
  // total = 172,624,896 bytes

  int*    idxb   = (int*)(ws + IDX_O);
  float*  bcq    = (float*)(ws + BCQ_O);
  __bf16* wcb    = (__bf16*)(ws + WCB_O);
  __bf16* kmat   = (__bf16*)(ws + KMAT_O);
  __bf16* vt     = (__bf16*)(ws + VT_O);
  __bf16* outwb  = (__bf16*)(ws + OUTWB_O);
  __bf16* gatewb = (__bf16*)(ws + GATEW_O);
  __bf16* intw1b = (__bf16*)(ws + INTW1_O);
  __bf16* intw2b = (__bf16*)(ws + INTW2_O);
  __bf16* qhb    = (__bf16*)(ws + QHB_O);
  __bf16* integb = (__bf16*)(ws + QHB_O);   // reuse: qh_bf dead after t1 GEMM
  __bf16* qb     = (__bf16*)(ws + QB_O);
  __bf16* sb     = (__bf16*)(ws + SB_O);
  __bf16* t1b    = (__bf16*)(ws + SB_O);    // reuse: S/P dead after ctx GEMM
  __bf16* ctxb   = (__bf16*)(ws + CTX_O);
  __bf16* attnb  = (__bf16*)(ws + ATTN_O);
  __bf16* gateb  = (__bf16*)(ws + GATE_O);

  // 1) convert qh + big weights to bf16
  cvt_kernel<<<22336, 256, 0, stream>>>(qh, outw, gw, w1, w2,
                                        qhb, outwb, gatewb, intw1b, intw2b);
  // 2) top-512
  topk_kernel<<<1, 256, 0, stream>>>(sel, idxb);
  // 3) folded Q-projection weight (with 1/8 softmax scale)
  wc_build<<<256, 256, 0, stream>>>(qp_w, qp_b, inw, inb, wcb, bcq);
  // 4) gather + LN + K,Vt
  kv_build<<<512, 256, 0, stream>>>(idxb, memk, inw, inb, ln1g, ln1b, kmat, vt);
  // 5) Q = qh_bf @ Wc^T + bcq   [16384 x 256], K=1024
  gemm_kernel<128, 128, 0><<<dim3(128, 2, 1), 256, 0, stream>>>(
      qhb, 1024, 1024, (const __bf16*)nullptr, 0, wcb, 1024, bcq, qb, 256, 1024, 0, 0, 0);
  // 6) S_h = Q_h @ K_h^T  (scale folded), per head  [16384 x 512], K=64
  gemm_kernel<128, 128, 1><<<dim3(128, 4, 4), 256, 0, stream>>>(
      qb, 256, 64, (const __bf16*)nullptr, 0, kmat, 256, (const float*)nullptr,
      sb, 512, 64, 64, 64, (long)16384 * 512);
  // 7) softmax in place (65536 rows of 512)
  softmax_kernel<<<16384, 256, 0, stream>>>(sb);
  // 8) ctx_h = P_h @ Vt_h^T  [16384 x 64], K=512
  gemm_kernel<128, 64, 1><<<dim3(128, 1, 4), 256, 0, stream>>>(
      sb, 512, 512, (const __bf16*)nullptr, 0, vt, 512, (const float*)nullptr,
      ctxb, 256, 512, (long)16384 * 512, (long)64 * 512, 64);
  // 9) attn_out = ctx @ out_w^T + out_b  [16384 x 256], K=256
  gemm_kernel<128, 128, 0><<<dim3(128, 2, 1), 256, 0, stream>>>(
      ctxb, 256, 256, (const __bf16*)nullptr, 0, outwb, 256, outb, attnb, 256, 256, 0, 0, 0);
  // 10) gate = sigmoid([qh,attn] @ gate_w^T + gate_b)  [16384 x 1024], K=1280
  gemm_kernel<128, 128, 2><<<dim3(128, 8, 1), 256, 0, stream>>>(
      qhb, 1024, 1024, attnb, 256, gatewb, 1280, gb, gateb, 1024, 1280, 0, 0, 0);
  // 11) t1 = [qh,attn] @ int_w1^T + int_b1  [16384 x 2048], K=1280
  gemm_kernel<128, 128, 0><<<dim3(128, 16, 1), 256, 0, stream>>>(
      qhb, 1024, 1024, attnb, 256, intw1b, 1280, b1, t1b, 2048, 1280, 0, 0, 0);
  // 12) h = gelu(LN(t1)) in place
  ln_gelu_kernel<<<16384, 256, 0, stream>>>(t1b, lng, lnb);
  // 13) integrated = h @ int_w2^T + int_b2  [16384 x 1024], K=2048
  gemm_kernel<128, 128, 0><<<dim3(128, 8, 1), 256, 0, stream>>>(
      t1b, 2048, 2048, (const __bf16*)nullptr, 0, intw2b, 2048, b2, integb, 1024, 2048, 0, 0, 0);
  // 14) out = LN(qh + gate*integrated; ln2)
  final_kernel<<<16384, 256, 0, stream>>>(qh, gateb, integb, ln2g, ln2b, out);
}

// Round 2
// 719.023 us; speedup vs baseline: 1.0788x; 1.0788x over previous
//
#include <hip/hip_runtime.h>
#include <math.h>

// ---------------------------------------------------------------------------
// MemoryRetriever: B=8, S=2048 (N=16384 rows), H=1024, M=256, NH=4, HD=64,
// NM=4096, K_SEL=512. fp32 I/O, bf16 MFMA internals (2%-of-max threshold).
// R2: m97-style GEMM (global_load_lds width=16, unpadded LDS), shuffle-based
//     LN reductions, tanh-form gelu.
// ---------------------------------------------------------------------------

typedef __bf16 bf16x8 __attribute__((ext_vector_type(8)));
typedef __bf16 bf16x4 __attribute__((ext_vector_type(4)));
typedef float  floatx4 __attribute__((ext_vector_type(4)));

#define NMEM   4096
#define KSEL   512

__device__ __forceinline__ void gl_lds16(const __bf16* g, __bf16* l) {
  __builtin_amdgcn_global_load_lds(
      (const __attribute__((address_space(1))) void*)g,
      (__attribute__((address_space(3))) void*)l, 16, 0, 0);
}

// ---------------------------------------------------------------------------
// 1) fp32 -> bf16 conversion of qh + big weights (one pass, float4 chunks)
// ---------------------------------------------------------------------------
__global__ void cvt_kernel(const float* __restrict__ s0, const float* __restrict__ s1,
                           const float* __restrict__ s2, const float* __restrict__ s3,
                           const float* __restrict__ s4,
                           __bf16* __restrict__ d0, __bf16* __restrict__ d1,
                           __bf16* __restrict__ d2, __bf16* __restrict__ d3,
                           __bf16* __restrict__ d4) {
  long q = (long)blockIdx.x * 256 + threadIdx.x;  // quad index
  const long n0 = 16777216 / 4, n1 = 65536 / 4, n2 = 1310720 / 4,
             n3 = 2621440 / 4, n4 = 2097152 / 4;
  const float* s; __bf16* d; long off;
  if (q < n0) { s = s0; d = d0; off = q; }
  else if ((q -= n0) < n1) { s = s1; d = d1; off = q; }
  else if ((q -= n1) < n2) { s = s2; d = d2; off = q; }
  else if ((q -= n2) < n3) { s = s3; d = d3; off = q; }
  else if ((q -= n3) < n4) { s = s4; d = d4; off = q; }
  else return;
  float4 v = ((const float4*)s)[off];
  bf16x4 o;
  o[0] = (__bf16)v.x; o[1] = (__bf16)v.y; o[2] = (__bf16)v.z; o[3] = (__bf16)v.w;
  ((bf16x4*)d)[off] = o;
}

// ---------------------------------------------------------------------------
// 2) top-512 of 4096 scores: radix-select on order-mapped float bits.
// ---------------------------------------------------------------------------
__device__ __forceinline__ unsigned mapbits(float x) {
  unsigned b = __float_as_uint(x);
  return (b & 0x80000000u) ? ~b : (b | 0x80000000u);
}

__global__ void topk_kernel(const float* __restrict__ scores, int* __restrict__ idx_out) {
  const int n = NMEM, k = KSEL;
  __shared__ int hist[256];
  __shared__ int s_need;
  __shared__ unsigned s_prefix;
  __shared__ int s_cnt_gt, s_ntie;
  __shared__ int tie[1024];
  int tid = threadIdx.x;  // 256 threads
  if (tid == 0) { s_need = k; s_prefix = 0; s_cnt_gt = 0; s_ntie = 0; }
  __syncthreads();
  for (int pass = 0; pass < 4; ++pass) {
    if (tid < 256) hist[tid] = 0;
    __syncthreads();
    int shift = 24 - 8 * pass;
    unsigned pref = s_prefix;
    for (int i = tid; i < n; i += 256) {
      unsigned u = mapbits(scores[i]);
      bool in = (pass == 0) || ((u >> (shift + 8)) == pref);
      if (in) atomicAdd(&hist[(u >> shift) & 255], 1);
    }
    __syncthreads();
    if (tid == 0) {
      int need = s_need, above = 0, b = 255;
      for (;; --b) {
        int c = hist[b];
        if (above + c >= need) { s_need = need - above; break; }
        above += c;
      }
      s_prefix = (s_prefix << 8) | (unsigned)b;
    }
    __syncthreads();
  }
  unsigned T = s_prefix;
  int need = s_need;
  for (int i = tid; i < n; i += 256) {
    unsigned u = mapbits(scores[i]);
    if (u > T) { int p = atomicAdd(&s_cnt_gt, 1); idx_out[p] = i; }
    else if (u == T) { int t = atomicAdd(&s_ntie, 1); if (t < 1024) tie[t] = i; }
  }
  __syncthreads();
  int base = s_cnt_gt;
  int nt = s_ntie < 1024 ? s_ntie : 1024;
  for (int j = tid; j < nt; j += 256) {
    int my = tie[j], rank = 0;
    for (int l = 0; l < nt; ++l) rank += (tie[l] < my) ? 1 : 0;
    if (rank < need) idx_out[base + rank] = my;
  }
}

// ---------------------------------------------------------------------------
// 3) Wc = 0.125 * (wq @ qp_w)  [256 x 1024] bf16 ;  bcq = 0.125*(wq@qp_b + bq)
// ---------------------------------------------------------------------------
__global__ void wc_build(const float* __restrict__ qp_w, const float* __restrict__ qp_b,
                         const float* __restrict__ in_w, const float* __restrict__ in_b,
                         __bf16* __restrict__ Wc, float* __restrict__ bcq) {
  int i = blockIdx.x, t = threadIdx.x;  // 256 blocks x 256 threads
  const float* wq = in_w + (long)i * 256;
  float a0 = 0, a1 = 0, a2 = 0, a3 = 0;
  for (int s = 0; s < 256; ++s) {
    float wv = wq[s];
    const float* qr = qp_w + (long)s * 1024 + t;
    a0 += wv * qr[0];   a1 += wv * qr[256];
    a2 += wv * qr[512]; a3 += wv * qr[768];
  }
  __bf16* wr = Wc + (long)i * 1024 + t;
  wr[0]   = (__bf16)(0.125f * a0); wr[256] = (__bf16)(0.125f * a1);
  wr[512] = (__bf16)(0.125f * a2); wr[768] = (__bf16)(0.125f * a3);
  if (t == 0) {
    float s = in_b[i];
    for (int j = 0; j < 256; ++j) s += wq[j] * qp_b[j];
    bcq[i] = 0.125f * s;
  }
}

// ---------------------------------------------------------------------------
// 4) gather + LN(ln1) + K / V projections. K row-major [512,256] bf16;
//    V transposed: Vt[h][d][key] = [4][64][512] bf16.
// ---------------------------------------------------------------------------
__global__ void kv_build(const int* __restrict__ idx, const float* __restrict__ mem_keys,
                         const float* __restrict__ in_w, const float* __restrict__ in_b,
                         const float* __restrict__ ln1g, const float* __restrict__ ln1b,
                         __bf16* __restrict__ Kmat, __bf16* __restrict__ Vt) {
  int r = blockIdx.x, t = threadIdx.x;  // 512 blocks x 256 threads
  int lane = t & 63, wave = t >> 6;
  __shared__ float wred[8];
  __shared__ float m[256];
  int row = idx[r];
  float x = mem_keys[(long)row * 256 + t];
  float s = x;
  #pragma unroll
  for (int o = 32; o > 0; o >>= 1) s += __shfl_xor(s, o);
  if (lane == 0) wred[wave] = s;
  __syncthreads();
  float mu = (wred[0] + wred[1] + wred[2] + wred[3]) / 256.0f;
  float e = x - mu;
  s = e * e;
  #pragma unroll
  for (int o = 32; o > 0; o >>= 1) s += __shfl_xor(s, o);
  if (lane == 0) wred[4 + wave] = s;
  __syncthreads();
  float rstd = rsqrtf((wred[4] + wred[5] + wred[6] + wred[7]) / 256.0f + 1e-5f);
  m[t] = e * rstd * ln1g[t] + ln1b[t];
  __syncthreads();
  float ka = 0.f, va = 0.f;
  const float* wk = in_w + (long)(256 + t) * 256;
  const float* wv = in_w + (long)(512 + t) * 256;
  #pragma unroll 4
  for (int i = 0; i < 256; i += 4) {
    float4 wkv = *(const float4*)(wk + i);
    float4 wvv = *(const float4*)(wv + i);
    ka += m[i] * wkv.x + m[i + 1] * wkv.y + m[i + 2] * wkv.z + m[i + 3] * wkv.w;
    va += m[i] * wvv.x + m[i + 1] * wvv.y + m[i + 2] * wvv.z + m[i + 3] * wvv.w;
  }
  ka += in_b[256 + t]; va += in_b[512 + t];
  Kmat[(long)r * 256 + t] = (__bf16)ka;
  Vt[(long)(t >> 6) * (64 * 512) + (long)(t & 63) * 512 + r] = (__bf16)va;
}

// ---------------------------------------------------------------------------
// 5) m97-style bf16 MFMA GEMM: C = epi( X[M x Ktot] · W[N x Ktot]^T + bias )
//    global_load_lds width=16 staging into UNPADDED LDS tiles (wave-uniform
//    base + lane*16 constraint), 16x16x32 MFMA, BK=64, 4 waves 2x2.
//    X split in two K-segments (K1 | 64, so each K-tile is segment-uniform).
//    EPI: 0=bias, 1=none, 2=bias+sigmoid.
// ---------------------------------------------------------------------------
template <int BM, int BN, int EPI>
__launch_bounds__(256, 3)
__global__ void gemm_kernel(const __bf16* __restrict__ X1, int ldx1, int K1,
                            const __bf16* __restrict__ X2, int ldx2,
                            const __bf16* __restrict__ W, int ldw,
                            const float* __restrict__ bias,
                            __bf16* __restrict__ C, int ldc, int Ktot,
                            long sXz, long sWz, long sCz) {
  constexpr int BK = 64;
  __shared__ __bf16 As[BM * BK];
  __shared__ __bf16 Bs[BN * BK];
  const int tid = threadIdx.x;
  const int lane = tid & 63, wave = tid >> 6;
  const int wm = wave >> 1, wn = wave & 1;
  constexpr int FM = (BM / 2) / 16, FN = (BN / 2) / 16;
  floatx4 acc[FM][FN];
  #pragma unroll
  for (int i = 0; i < FM; ++i)
    #pragma unroll
    for (int j = 0; j < FN; ++j)
      #pragma unroll
      for (int r = 0; r < 4; ++r) acc[i][j][r] = 0.0f;

  const long z = blockIdx.z;
  const __bf16* x1 = X1 + z * sXz;
  const __bf16* w  = W + z * sWz;
  __bf16* c = C + z * sCz;
  const long row0 = (long)blockIdx.x * BM;
  const int col0 = blockIdx.y * BN;
  const int nKt = Ktot / BK;
  const int srow = lane >> 3;        // 0..7 : row within 8-row chunk
  const int scol = (lane & 7) * 8;   // 0,8,..,56 : col within BK

  for (int kt = 0; kt < nKt; ++kt) {
    const int k0 = kt * BK;
    const __bf16* xb; long xld; int kx;  // segment select (wave-uniform)
    if (k0 < K1) { xb = x1; xld = ldx1; kx = k0; }
    else         { xb = X2; xld = ldx2; kx = k0 - K1; }
    #pragma unroll
    for (int i = 0; i < BM / 32; ++i) {  // A: BM/8 chunks of 8 rows x 64 cols
      int chunk = wave * (BM / 32) + i;
      const __bf16* g = xb + (row0 + chunk * 8 + srow) * xld + kx + scol;
      gl_lds16(g, As + chunk * 512);
    }
    #pragma unroll
    for (int i = 0; i < BN / 32; ++i) {
      int chunk = wave * (BN / 32) + i;
      const __bf16* g = w + (long)(col0 + chunk * 8 + srow) * ldw + k0 + scol;
      gl_lds16(g, Bs + chunk * 512);
    }
    __syncthreads();
    #pragma unroll
    for (int kk = 0; kk < 2; ++kk) {
      bf16x8 a[FM], b[FN];
      const int koff = kk * 32 + (lane >> 4) * 8;
      #pragma unroll
      for (int fm = 0; fm < FM; ++fm)
        a[fm] = *(const bf16x8*)(As + (wm * (BM / 2) + fm * 16 + (lane & 15)) * BK + koff);
      #pragma unroll
      for (int fn = 0; fn < FN; ++fn)
        b[fn] = *(const bf16x8*)(Bs + (wn * (BN / 2) + fn * 16 + (lane & 15)) * BK + koff);
      #pragma unroll
      for (int fm = 0; fm < FM; ++fm)
        #pragma unroll
        for (int fn = 0; fn < FN; ++fn)
          acc[fm][fn] = __builtin_amdgcn_mfma_f32_16x16x32_bf16(a[fm], b[fn], acc[fm][fn], 0, 0, 0);
    }
    __syncthreads();
  }
  // epilogue: C/D layout col = lane&15, row = (lane>>4)*4 + r
  #pragma unroll
  for (int fn = 0; fn < FN; ++fn) {
    const int col = col0 + wn * (BN / 2) + fn * 16 + (lane & 15);
    float bv = (EPI == 1) ? 0.0f : bias[col];
    #pragma unroll
    for (int fm = 0; fm < FM; ++fm) {
      #pragma unroll
      for (int r = 0; r < 4; ++r) {
        long row = row0 + wm * (BM / 2) + fm * 16 + (lane >> 4) * 4 + r;
        float v = acc[fm][fn][r] + bv;
        if (EPI == 2) v = 1.0f / (1.0f + __expf(-v));
        c[row * (long)ldc + col] = (__bf16)v;
      }
    }
  }
}

// ---------------------------------------------------------------------------
// 6) softmax over 512 keys, in-place on bf16 S (one wave per row)
// ---------------------------------------------------------------------------
__global__ void softmax_kernel(__bf16* __restrict__ S) {
  long row = (long)blockIdx.x * 4 + (threadIdx.x >> 6);
  int lane = threadIdx.x & 63;
  __bf16* p = S + row * 512 + lane * 8;
  bf16x8 v = *(const bf16x8*)p;
  float f[8], mx = -1e30f;
  #pragma unroll
  for (int j = 0; j < 8; ++j) { f[j] = (float)v[j]; mx = fmaxf(mx, f[j]); }
  #pragma unroll
  for (int o = 32; o > 0; o >>= 1) mx = fmaxf(mx, __shfl_xor(mx, o));
  float s = 0.f;
  #pragma unroll
  for (int j = 0; j < 8; ++j) { f[j] = __expf(f[j] - mx); s += f[j]; }
  #pragma unroll
  for (int o = 32; o > 0; o >>= 1) s += __shfl_xor(s, o);
  float inv = 1.0f / s;
  bf16x8 o8;
  #pragma unroll
  for (int j = 0; j < 8; ++j) o8[j] = (__bf16)(f[j] * inv);
  *(bf16x8*)p = o8;
}

// ---------------------------------------------------------------------------
// 7) LN(int_ln) + gelu (tanh form), in-place on t1 rows of 2048.
//    Shuffle reductions: 2 barriers total.
// ---------------------------------------------------------------------------
__global__ void ln_gelu_kernel(__bf16* __restrict__ T1, const float* __restrict__ g,
                               const float* __restrict__ b) {
  long row = blockIdx.x; int t = threadIdx.x;  // 256 threads, 8 elems each
  int lane = t & 63, wave = t >> 6;
  __shared__ float wred[8];
  __bf16* p = T1 + row * 2048 + t * 8;
  bf16x8 v = *(const bf16x8*)p;
  float f[8], s = 0.f;
  #pragma unroll
  for (int j = 0; j < 8; ++j) { f[j] = (float)v[j]; s += f[j]; }
  #pragma unroll
  for (int o = 32; o > 0; o >>= 1) s += __shfl_xor(s, o);
  if (lane == 0) wred[wave] = s;
  __syncthreads();
  float mu = (wred[0] + wred[1] + wred[2] + wred[3]) / 2048.0f;
  s = 0.f;
  #pragma unroll
  for (int j = 0; j < 8; ++j) { f[j] -= mu; s += f[j] * f[j]; }
  #pragma unroll
  for (int o = 32; o > 0; o >>= 1) s += __shfl_xor(s, o);
  if (lane == 0) wred[4 + wave] = s;
  __syncthreads();
  float rstd = rsqrtf((wred[4] + wred[5] + wred[6] + wred[7]) / 2048.0f + 1e-5f);
  float4 g0 = *(const float4*)(g + t * 8), g1 = *(const float4*)(g + t * 8 + 4);
  float4 b0 = *(const float4*)(b + t * 8), b1 = *(const float4*)(b + t * 8 + 4);
  float gg[8] = { g0.x, g0.y, g0.z, g0.w, g1.x, g1.y, g1.z, g1.w };
  float bb[8] = { b0.x, b0.y, b0.z, b0.w, b1.x, b1.y, b1.z, b1.w };
  bf16x8 o8;
  #pragma unroll
  for (int j = 0; j < 8; ++j) {
    float y = f[j] * rstd * gg[j] + bb[j];
    // gelu(y) ~= y * sigmoid(1.5957691*(y + 0.044715 y^3)), max err ~3e-4
    float u = 1.5957691216057308f * (y + 0.044715f * y * y * y);
    o8[j] = (__bf16)(y / (1.0f + __expf(-u)));
  }
  *(bf16x8*)p = o8;
}

// ---------------------------------------------------------------------------
// 8) out = LN(qh + gate*integrated; ln2)  (fp32 out), rows of 1024
// ---------------------------------------------------------------------------
__global__ void final_kernel(const float* __restrict__ qh, const __bf16* __restrict__ gate,
                             const __bf16* __restrict__ integ, const float* __restrict__ g,
                             const float* __restrict__ b, float* __restrict__ out) {
  long row = blockIdx.x; int t = threadIdx.x;  // 256 threads, 4 elems each
  int lane = t & 63, wave = t >> 6;
  __shared__ float wred[8];
  long base = row * 1024 + t * 4;
  float4 q = *(const float4*)(qh + base);
  bf16x4 gv = *(const bf16x4*)(gate + base);
  bf16x4 iv = *(const bf16x4*)(integ + base);
  float f[4] = { q.x + (float)gv[0] * (float)iv[0], q.y + (float)gv[1] * (float)iv[1],
                 q.z + (float)gv[2] * (float)iv[2], q.w + (float)gv[3] * (float)iv[3] };
  float s = f[0] + f[1] + f[2] + f[3];
  #pragma unroll
  for (int o = 32; o > 0; o >>= 1) s += __shfl_xor(s, o);
  if (lane == 0) wred[wave] = s;
  __syncthreads();
  float mu = (wred[0] + wred[1] + wred[2] + wred[3]) / 1024.0f;
  s = 0.f;
  #pragma unroll
  for (int j = 0; j < 4; ++j) { f[j] -= mu; s += f[j] * f[j]; }
  #pragma unroll
  for (int o = 32; o > 0; o >>= 1) s += __shfl_xor(s, o);
  if (lane == 0) wred[4 + wave] = s;
  __syncthreads();
  float rstd = rsqrtf((wred[4] + wred[5] + wred[6] + wred[7]) / 1024.0f + 1e-5f);
  float4 gv4 = *(const float4*)(g + t * 4);
  float4 bv4 = *(const float4*)(b + t * 4);
  float4 ov;
  ov.x = f[0] * rstd * gv4.x + bv4.x;
  ov.y = f[1] * rstd * gv4.y + bv4.y;
  ov.z = f[2] * rstd * gv4.z + bv4.z;
  ov.w = f[3] * rstd * gv4.w + bv4.w;
  *(float4*)(out + base) = ov;
}

// ---------------------------------------------------------------------------
// launch
// ---------------------------------------------------------------------------
extern "C" void kernel_launch(void* const* d_in, const int* in_sizes, int n_in,
                              void* d_out, int out_size, void* d_ws, size_t ws_size,
                              hipStream_t stream) {
  const float* qh   = (const float*)d_in[0];
  const float* memk = (const float*)d_in[1];
  const float* sel  = (const float*)d_in[2];
  const float* qp_w = (const float*)d_in[3];
  const float* qp_b = (const float*)d_in[4];
  const float* inw  = (const float*)d_in[5];
  const float* inb  = (const float*)d_in[6];
  const float* outw = (const float*)d_in[7];
  const float* outb = (const float*)d_in[8];
  const float* gw   = (const float*)d_in[9];
  const float* gb   = (const float*)d_in[10];
  const float* w1   = (const float*)d_in[11];
  const float* b1   = (const float*)d_in[12];
  const float* lng  = (const float*)d_in[13];
  const float* lnb  = (const float*)d_in[14];
  const float* w2   = (const float*)d_in[15];
  const float* b2   = (const float*)d_in[16];
  const float* ln1g = (const float*)d_in[17];
  const float* ln1b = (const float*)d_in[18];
  const float* ln2g = (const float*)d_in[19];
  const float* ln2b = (const float*)d_in[20];
  float* out = (float*)d_out;
  char* ws = (char*)d_ws;

  // workspace arena (bytes); lifetimes: t1 overlays S/P, integ overlays qh_bf
  const size_t IDX_O   = 0;          // 512*4
  const size_t BCQ_O   = 2048;       // 256*4
  const size_t WCB_O   = 3072;       // 256*1024*2   = 524288
  const size_t KMAT_O  = 527360;     // 512*256*2    = 262144
  const size_t VT_O    = 789504;     // 4*64*512*2   = 262144
  const size_t OUTWB_O = 1051648;    // 65536*2      = 131072
  const size_t GATEW_O = 1182720;    // 1310720*2    = 2621440
  const size_t INTW1_O = 3804160;    // 2621440*2    = 5242880
  const size_t INTW2_O = 9047040;    // 2097152*2    = 4194304
  const size_t QHB_O   = 13241344;   // 16777216*2   = 33554432  (later: integrated)
  const size_t QB_O    = 46795776;   // 16384*256*2  = 8388608
  const size_t SB_O    = 55184384;   // 4*16384*512*2= 67108864  (later: t1)
  const size_t CTX_O   = 122293248;  // 8388608
  const size_t ATTN_O  = 130681856;  // 8388608
  const size_t GATE_O  = 139070464;  // 33554432
  // total = 172,624,896 bytes

  int*    idxb   = (int*)(ws + IDX_O);
  float*  bcq    = (float*)(ws + BCQ_O);
  __bf16* wcb    = (__bf16*)(ws + WCB_O);
  __bf16* kmat   = (__bf16*)(ws + KMAT_O);
  __bf16* vt     = (__bf16*)(ws + VT_O);
  __bf16* outwb  = (__bf16*)(ws + OUTWB_O);
  __bf16* gatewb = (__bf16*)(ws + GATEW_O);
  __bf16* intw1b = (__bf16*)(ws + INTW1_O);
  __bf16* intw2b = (__bf16*)(ws + INTW2_O);
  __bf16* qhb    = (__bf16*)(ws + QHB_O);
  __bf16* integb = (__bf16*)(ws + QHB_O);   // reuse: qh_bf dead after t1 GEMM
  __bf16* qb     = (__bf16*)(ws + QB_O);
  __bf16* sb     = (__bf16*)(ws + SB_O);
  __bf16* t1b    = (__bf16*)(ws + SB_O);    // reuse: S/P dead after ctx GEMM
  __bf16* ctxb   = (__bf16*)(ws + CTX_O);
  __bf16* attnb  = (__bf16*)(ws + ATTN_O);
  __bf16* gateb  = (__bf16*)(ws + GATE_O);

  // 1) convert qh + big weights to bf16
  cvt_kernel<<<22336, 256, 0, stream>>>(qh, outw, gw, w1, w2,
                                        qhb, outwb, gatewb, intw1b, intw2b);
  // 2) top-512
  topk_kernel<<<1, 256, 0, stream>>>(sel, idxb);
  // 3) folded Q-projection weight (with 1/8 softmax scale)
  wc_build<<<256, 256, 0, stream>>>(qp_w, qp_b, inw, inb, wcb, bcq);
  // 4) gather + LN + K,Vt
  kv_build<<<512, 256, 0, stream>>>(idxb, memk, inw, inb, ln1g, ln1b, kmat, vt);
  // 5) Q = qh_bf @ Wc^T + bcq   [16384 x 256], K=1024
  gemm_kernel<128, 128, 0><<<dim3(128, 2, 1), 256, 0, stream>>>(
      qhb, 1024, 1024, (const __bf16*)nullptr, 0, wcb, 1024, bcq, qb, 256, 1024, 0, 0, 0);
  // 6) S_h = Q_h @ K_h^T  (scale folded), per head  [16384 x 512], K=64
  gemm_kernel<128, 128, 1><<<dim3(128, 4, 4), 256, 0, stream>>>(
      qb, 256, 64, (const __bf16*)nullptr, 0, kmat, 256, (const float*)nullptr,
      sb, 512, 64, 64, 64, (long)16384 * 512);
  // 7) softmax in place (65536 rows of 512)
  softmax_kernel<<<16384, 256, 0, stream>>>(sb);
  // 8) ctx_h = P_h @ Vt_h^T  [16384 x 64], K=512
  gemm_kernel<128, 64, 1><<<dim3(128, 1, 4), 256, 0, stream>>>(
      sb, 512, 512, (const __bf16*)nullptr, 0, vt, 512, (const float*)nullptr,
      ctxb, 256, 512, (long)16384 * 512, (long)64 * 512, 64);
  // 9) attn_out = ctx @ out_w^T + out_b  [16384 x 256], K=256
  gemm_kernel<128, 128, 0><<<dim3(128, 2, 1), 256, 0, stream>>>(
      ctxb, 256, 256, (const __bf16*)nullptr, 0, outwb, 256, outb, attnb, 256, 256, 0, 0, 0);
  // 10) gate = sigmoid([qh,attn] @ gate_w^T + gate_b)  [16384 x 1024], K=1280
  gemm_kernel<128, 128, 2><<<dim3(128, 8, 1), 256, 0, stream>>>(
      qhb, 1024, 1024, attnb, 256, gatewb, 1280, gb, gateb, 1024, 1280, 0, 0, 0);
  // 11) t1 = [qh,attn] @ int_w1^T + int_b1  [16384 x 2048], K=1280
  gemm_kernel<128, 128, 0><<<dim3(128, 16, 1), 256, 0, stream>>>(
      qhb, 1024, 1024, attnb, 256, intw1b, 1280, b1, t1b, 2048, 1280, 0, 0, 0);
  // 12) h = gelu(LN(t1)) in place
  ln_gelu_kernel<<<16384, 256, 0, stream>>>(t1b, lng, lnb);
  // 13) integrated = h @ int_w2^T + int_b2  [16384 x 1024], K=2048
  gemm_kernel<128, 128, 0><<<dim3(128, 8, 1), 256, 0, stream>>>(
      t1b, 2048, 2048, (const __bf16*)nullptr, 0, intw2b, 2048, b2, integb, 1024, 2048, 0, 0, 0);
  // 14) out = LN(qh + gate*integrated; ln2)
  final_kernel<<<16384, 256, 0, stream>>>(qh, gateb, integb, ln2g, ln2b, out);
}

// Round 3
// 633.664 us; speedup vs baseline: 1.2242x; 1.1347x over previous
//
#include <hip/hip_runtime.h>
#include <math.h>

// ---------------------------------------------------------------------------
// MemoryRetriever: B=8, S=2048 (N=16384 rows), H=1024, M=256, NH=4, HD=64,
// NM=4096, K_SEL=512. fp32 I/O, bf16 MFMA internals (2%-of-max threshold).
// R3: XOR-swizzled LDS layout in the GEMM (kills the 16-way bank conflicts
//     caused by the 128B row stride, while keeping global_load_lds staging:
//     we permute which global chunk each lane fetches, not the LDS dst).
// ---------------------------------------------------------------------------

typedef __bf16 bf16x8 __attribute__((ext_vector_type(8)));
typedef __bf16 bf16x4 __attribute__((ext_vector_type(4)));
typedef float  floatx4 __attribute__((ext_vector_type(4)));

#define NMEM   4096
#define KSEL   512

__device__ __forceinline__ void gl_lds16(const __bf16* g, __bf16* l) {
  __builtin_amdgcn_global_load_lds(
      (const __attribute__((address_space(1))) void*)g,
      (__attribute__((address_space(3))) void*)l, 16, 0, 0);
}

// ---------------------------------------------------------------------------
// 1) fp32 -> bf16 conversion of qh + big weights (one pass, float4 chunks)
// ---------------------------------------------------------------------------
__global__ void cvt_kernel(const float* __restrict__ s0, const float* __restrict__ s1,
                           const float* __restrict__ s2, const float* __restrict__ s3,
                           const float* __restrict__ s4,
                           __bf16* __restrict__ d0, __bf16* __restrict__ d1,
                           __bf16* __restrict__ d2, __bf16* __restrict__ d3,
                           __bf16* __restrict__ d4) {
  long q = (long)blockIdx.x * 256 + threadIdx.x;  // quad index
  const long n0 = 16777216 / 4, n1 = 65536 / 4, n2 = 1310720 / 4,
             n3 = 2621440 / 4, n4 = 2097152 / 4;
  const float* s; __bf16* d; long off;
  if (q < n0) { s = s0; d = d0; off = q; }
  else if ((q -= n0) < n1) { s = s1; d = d1; off = q; }
  else if ((q -= n1) < n2) { s = s2; d = d2; off = q; }
  else if ((q -= n2) < n3) { s = s3; d = d3; off = q; }
  else if ((q -= n3) < n4) { s = s4; d = d4; off = q; }
  else return;
  float4 v = ((const float4*)s)[off];
  bf16x4 o;
  o[0] = (__bf16)v.x; o[1] = (__bf16)v.y; o[2] = (__bf16)v.z; o[3] = (__bf16)v.w;
  ((bf16x4*)d)[off] = o;
}

// ---------------------------------------------------------------------------
// 2) top-512 of 4096 scores: radix-select on order-mapped float bits.
// ---------------------------------------------------------------------------
__device__ __forceinline__ unsigned mapbits(float x) {
  unsigned b = __float_as_uint(x);
  return (b & 0x80000000u) ? ~b : (b | 0x80000000u);
}

__global__ void topk_kernel(const float* __restrict__ scores, int* __restrict__ idx_out) {
  const int n = NMEM, k = KSEL;
  __shared__ int hist[256];
  __shared__ int s_need;
  __shared__ unsigned s_prefix;
  __shared__ int s_cnt_gt, s_ntie;
  __shared__ int tie[1024];
  int tid = threadIdx.x;  // 256 threads
  if (tid == 0) { s_need = k; s_prefix = 0; s_cnt_gt = 0; s_ntie = 0; }
  __syncthreads();
  for (int pass = 0; pass < 4; ++pass) {
    if (tid < 256) hist[tid] = 0;
    __syncthreads();
    int shift = 24 - 8 * pass;
    unsigned pref = s_prefix;
    for (int i = tid; i < n; i += 256) {
      unsigned u = mapbits(scores[i]);
      bool in = (pass == 0) || ((u >> (shift + 8)) == pref);
      if (in) atomicAdd(&hist[(u >> shift) & 255], 1);
    }
    __syncthreads();
    if (tid == 0) {
      int need = s_need, above = 0, b = 255;
      for (;; --b) {
        int c = hist[b];
        if (above + c >= need) { s_need = need - above; break; }
        above += c;
      }
      s_prefix = (s_prefix << 8) | (unsigned)b;
    }
    __syncthreads();
  }
  unsigned T = s_prefix;
  int need = s_need;
  for (int i = tid; i < n; i += 256) {
    unsigned u = mapbits(scores[i]);
    if (u > T) { int p = atomicAdd(&s_cnt_gt, 1); idx_out[p] = i; }
    else if (u == T) { int t = atomicAdd(&s_ntie, 1); if (t < 1024) tie[t] = i; }
  }
  __syncthreads();
  int base = s_cnt_gt;
  int nt = s_ntie < 1024 ? s_ntie : 1024;
  for (int j = tid; j < nt; j += 256) {
    int my = tie[j], rank = 0;
    for (int l = 0; l < nt; ++l) rank += (tie[l] < my) ? 1 : 0;
    if (rank < need) idx_out[base + rank] = my;
  }
}

// ---------------------------------------------------------------------------
// 3) Wc = 0.125 * (wq @ qp_w)  [256 x 1024] bf16 ;  bcq = 0.125*(wq@qp_b + bq)
// ---------------------------------------------------------------------------
__global__ void wc_build(const float* __restrict__ qp_w, const float* __restrict__ qp_b,
                         const float* __restrict__ in_w, const float* __restrict__ in_b,
                         __bf16* __restrict__ Wc, float* __restrict__ bcq) {
  int i = blockIdx.x, t = threadIdx.x;  // 256 blocks x 256 threads
  const float* wq = in_w + (long)i * 256;
  float a0 = 0, a1 = 0, a2 = 0, a3 = 0;
  for (int s = 0; s < 256; ++s) {
    float wv = wq[s];
    const float* qr = qp_w + (long)s * 1024 + t;
    a0 += wv * qr[0];   a1 += wv * qr[256];
    a2 += wv * qr[512]; a3 += wv * qr[768];
  }
  __bf16* wr = Wc + (long)i * 1024 + t;
  wr[0]   = (__bf16)(0.125f * a0); wr[256] = (__bf16)(0.125f * a1);
  wr[512] = (__bf16)(0.125f * a2); wr[768] = (__bf16)(0.125f * a3);
  if (t == 0) {
    float s = in_b[i];
    for (int j = 0; j < 256; ++j) s += wq[j] * qp_b[j];
    bcq[i] = 0.125f * s;
  }
}

// ---------------------------------------------------------------------------
// 4) gather + LN(ln1) + K / V projections. K row-major [512,256] bf16;
//    V transposed: Vt[h][d][key] = [4][64][512] bf16.
// ---------------------------------------------------------------------------
__global__ void kv_build(const int* __restrict__ idx, const float* __restrict__ mem_keys,
                         const float* __restrict__ in_w, const float* __restrict__ in_b,
                         const float* __restrict__ ln1g, const float* __restrict__ ln1b,
                         __bf16* __restrict__ Kmat, __bf16* __restrict__ Vt) {
  int r = blockIdx.x, t = threadIdx.x;  // 512 blocks x 256 threads
  int lane = t & 63, wave = t >> 6;
  __shared__ float wred[8];
  __shared__ float m[256];
  int row = idx[r];
  float x = mem_keys[(long)row * 256 + t];
  float s = x;
  #pragma unroll
  for (int o = 32; o > 0; o >>= 1) s += __shfl_xor(s, o);
  if (lane == 0) wred[wave] = s;
  __syncthreads();
  float mu = (wred[0] + wred[1] + wred[2] + wred[3]) / 256.0f;
  float e = x - mu;
  s = e * e;
  #pragma unroll
  for (int o = 32; o > 0; o >>= 1) s += __shfl_xor(s, o);
  if (lane == 0) wred[4 + wave] = s;
  __syncthreads();
  float rstd = rsqrtf((wred[4] + wred[5] + wred[6] + wred[7]) / 256.0f + 1e-5f);
  m[t] = e * rstd * ln1g[t] + ln1b[t];
  __syncthreads();
  float ka = 0.f, va = 0.f;
  const float* wk = in_w + (long)(256 + t) * 256;
  const float* wv = in_w + (long)(512 + t) * 256;
  #pragma unroll 4
  for (int i = 0; i < 256; i += 4) {
    float4 wkv = *(const float4*)(wk + i);
    float4 wvv = *(const float4*)(wv + i);
    ka += m[i] * wkv.x + m[i + 1] * wkv.y + m[i + 2] * wkv.z + m[i + 3] * wkv.w;
    va += m[i] * wvv.x + m[i + 1] * wvv.y + m[i + 2] * wvv.z + m[i + 3] * wvv.w;
  }
  ka += in_b[256 + t]; va += in_b[512 + t];
  Kmat[(long)r * 256 + t] = (__bf16)ka;
  Vt[(long)(t >> 6) * (64 * 512) + (long)(t & 63) * 512 + r] = (__bf16)va;
}

// ---------------------------------------------------------------------------
// 5) m97-style bf16 MFMA GEMM with XOR-swizzled LDS:
//    C = epi( X[M x Ktot] · W[N x Ktot]^T + bias ).
//    Staging: global_load_lds width=16; lane fetches (row=lane>>3,
//    cc=(lane&7)^(row&7)) so LDS slot r*64 + ((cc^(r&7))<<3) holds element
//    (r, cc*8..cc*8+7). Fragment reads then hit 8 distinct bank groups
//    (2-way aliasing = free) instead of one group 16-way.
//    EPI: 0=bias, 1=none, 2=bias+sigmoid.
// ---------------------------------------------------------------------------
template <int BM, int BN, int EPI>
__launch_bounds__(256, 4)
__global__ void gemm_kernel(const __bf16* __restrict__ X1, int ldx1, int K1,
                            const __bf16* __restrict__ X2, int ldx2,
                            const __bf16* __restrict__ W, int ldw,
                            const float* __restrict__ bias,
                            __bf16* __restrict__ C, int ldc, int Ktot,
                            long sXz, long sWz, long sCz) {
  constexpr int BK = 64;
  __shared__ __bf16 As[BM * BK];
  __shared__ __bf16 Bs[BN * BK];
  const int tid = threadIdx.x;
  const int lane = tid & 63, wave = tid >> 6;
  const int wm = wave >> 1, wn = wave & 1;
  constexpr int FM = (BM / 2) / 16, FN = (BN / 2) / 16;
  floatx4 acc[FM][FN];
  #pragma unroll
  for (int i = 0; i < FM; ++i)
    #pragma unroll
    for (int j = 0; j < FN; ++j)
      #pragma unroll
      for (int r = 0; r < 4; ++r) acc[i][j][r] = 0.0f;

  const long z = blockIdx.z;
  const __bf16* x1 = X1 + z * sXz;
  const __bf16* w  = W + z * sWz;
  __bf16* c = C + z * sCz;
  const long row0 = (long)blockIdx.x * BM;
  const int col0 = blockIdx.y * BN;
  const int nKt = Ktot / BK;
  const int srow = lane >> 3;                    // 0..7 : row within 8-row chunk
  const int scol = ((lane & 7) ^ srow) * 8;      // XOR-swizzled col chunk

  for (int kt = 0; kt < nKt; ++kt) {
    const int k0 = kt * BK;
    const __bf16* xb; long xld; int kx;  // segment select (wave-uniform)
    if (k0 < K1) { xb = x1; xld = ldx1; kx = k0; }
    else         { xb = X2; xld = ldx2; kx = k0 - K1; }
    #pragma unroll
    for (int i = 0; i < BM / 32; ++i) {  // A: chunks of 8 rows x 64 cols
      int chunk = wave * (BM / 32) + i;
      const __bf16* g = xb + (row0 + chunk * 8 + srow) * xld + kx + scol;
      gl_lds16(g, As + chunk * 512);
    }
    #pragma unroll
    for (int i = 0; i < BN / 32; ++i) {
      int chunk = wave * (BN / 32) + i;
      const __bf16* g = w + (long)(col0 + chunk * 8 + srow) * ldw + k0 + scol;
      gl_lds16(g, Bs + chunk * 512);
    }
    __syncthreads();
    #pragma unroll
    for (int kk = 0; kk < 2; ++kk) {
      bf16x8 a[FM], b[FN];
      const int ccq = kk * 4 + (lane >> 4);      // col-chunk index 0..7
      #pragma unroll
      for (int fm = 0; fm < FM; ++fm) {
        const int r = wm * (BM / 2) + fm * 16 + (lane & 15);
        a[fm] = *(const bf16x8*)(As + r * BK + ((ccq ^ (r & 7)) << 3));
      }
      #pragma unroll
      for (int fn = 0; fn < FN; ++fn) {
        const int r = wn * (BN / 2) + fn * 16 + (lane & 15);
        b[fn] = *(const bf16x8*)(Bs + r * BK + ((ccq ^ (r & 7)) << 3));
      }
      #pragma unroll
      for (int fm = 0; fm < FM; ++fm)
        #pragma unroll
        for (int fn = 0; fn < FN; ++fn)
          acc[fm][fn] = __builtin_amdgcn_mfma_f32_16x16x32_bf16(a[fm], b[fn], acc[fm][fn], 0, 0, 0);
    }
    __syncthreads();
  }
  // epilogue: C/D layout col = lane&15, row = (lane>>4)*4 + r
  #pragma unroll
  for (int fn = 0; fn < FN; ++fn) {
    const int col = col0 + wn * (BN / 2) + fn * 16 + (lane & 15);
    float bv = (EPI == 1) ? 0.0f : bias[col];
    #pragma unroll
    for (int fm = 0; fm < FM; ++fm) {
      #pragma unroll
      for (int r = 0; r < 4; ++r) {
        long row = row0 + wm * (BM / 2) + fm * 16 + (lane >> 4) * 4 + r;
        float v = acc[fm][fn][r] + bv;
        if (EPI == 2) v = 1.0f / (1.0f + __expf(-v));
        c[row * (long)ldc + col] = (__bf16)v;
      }
    }
  }
}

// ---------------------------------------------------------------------------
// 6) softmax over 512 keys, in-place on bf16 S (one wave per row)
// ---------------------------------------------------------------------------
__global__ void softmax_kernel(__bf16* __restrict__ S) {
  long row = (long)blockIdx.x * 4 + (threadIdx.x >> 6);
  int lane = threadIdx.x & 63;
  __bf16* p = S + row * 512 + lane * 8;
  bf16x8 v = *(const bf16x8*)p;
  float f[8], mx = -1e30f;
  #pragma unroll
  for (int j = 0; j < 8; ++j) { f[j] = (float)v[j]; mx = fmaxf(mx, f[j]); }
  #pragma unroll
  for (int o = 32; o > 0; o >>= 1) mx = fmaxf(mx, __shfl_xor(mx, o));
  float s = 0.f;
  #pragma unroll
  for (int j = 0; j < 8; ++j) { f[j] = __expf(f[j] - mx); s += f[j]; }
  #pragma unroll
  for (int o = 32; o > 0; o >>= 1) s += __shfl_xor(s, o);
  float inv = 1.0f / s;
  bf16x8 o8;
  #pragma unroll
  for (int j = 0; j < 8; ++j) o8[j] = (__bf16)(f[j] * inv);
  *(bf16x8*)p = o8;
}

// ---------------------------------------------------------------------------
// 7) LN(int_ln) + gelu (tanh form), in-place on t1 rows of 2048.
// ---------------------------------------------------------------------------
__global__ void ln_gelu_kernel(__bf16* __restrict__ T1, const float* __restrict__ g,
                               const float* __restrict__ b) {
  long row = blockIdx.x; int t = threadIdx.x;  // 256 threads, 8 elems each
  int lane = t & 63, wave = t >> 6;
  __shared__ float wred[8];
  __bf16* p = T1 + row * 2048 + t * 8;
  bf16x8 v = *(const bf16x8*)p;
  float f[8], s = 0.f;
  #pragma unroll
  for (int j = 0; j < 8; ++j) { f[j] = (float)v[j]; s += f[j]; }
  #pragma unroll
  for (int o = 32; o > 0; o >>= 1) s += __shfl_xor(s, o);
  if (lane == 0) wred[wave] = s;
  __syncthreads();
  float mu = (wred[0] + wred[1] + wred[2] + wred[3]) / 2048.0f;
  s = 0.f;
  #pragma unroll
  for (int j = 0; j < 8; ++j) { f[j] -= mu; s += f[j] * f[j]; }
  #pragma unroll
  for (int o = 32; o > 0; o >>= 1) s += __shfl_xor(s, o);
  if (lane == 0) wred[4 + wave] = s;
  __syncthreads();
  float rstd = rsqrtf((wred[4] + wred[5] + wred[6] + wred[7]) / 2048.0f + 1e-5f);
  float4 g0 = *(const float4*)(g + t * 8), g1 = *(const float4*)(g + t * 8 + 4);
  float4 b0 = *(const float4*)(b + t * 8), b1 = *(const float4*)(b + t * 8 + 4);
  float gg[8] = { g0.x, g0.y, g0.z, g0.w, g1.x, g1.y, g1.z, g1.w };
  float bb[8] = { b0.x, b0.y, b0.z, b0.w, b1.x, b1.y, b1.z, b1.w };
  bf16x8 o8;
  #pragma unroll
  for (int j = 0; j < 8; ++j) {
    float y = f[j] * rstd * gg[j] + bb[j];
    float u = 1.5957691216057308f * (y + 0.044715f * y * y * y);
    o8[j] = (__bf16)(y / (1.0f + __expf(-u)));
  }
  *(bf16x8*)p = o8;
}

// ---------------------------------------------------------------------------
// 8) out = LN(qh + gate*integrated; ln2)  (fp32 out), rows of 1024
// ---------------------------------------------------------------------------
__global__ void final_kernel(const float* __restrict__ qh, const __bf16* __restrict__ gate,
                             const __bf16* __restrict__ integ, const float* __restrict__ g,
                             const float* __restrict__ b, float* __restrict__ out) {
  long row = blockIdx.x; int t = threadIdx.x;  // 256 threads, 4 elems each
  int lane = t & 63, wave = t >> 6;
  __shared__ float wred[8];
  long base = row * 1024 + t * 4;
  float4 q = *(const float4*)(qh + base);
  bf16x4 gv = *(const bf16x4*)(gate + base);
  bf16x4 iv = *(const bf16x4*)(integ + base);
  float f[4] = { q.x + (float)gv[0] * (float)iv[0], q.y + (float)gv[1] * (float)iv[1],
                 q.z + (float)gv[2] * (float)iv[2], q.w + (float)gv[3] * (float)iv[3] };
  float s = f[0] + f[1] + f[2] + f[3];
  #pragma unroll
  for (int o = 32; o > 0; o >>= 1) s += __shfl_xor(s, o);
  if (lane == 0) wred[wave] = s;
  __syncthreads();
  float mu = (wred[0] + wred[1] + wred[2] + wred[3]) / 1024.0f;
  s = 0.f;
  #pragma unroll
  for (int j = 0; j < 4; ++j) { f[j] -= mu; s += f[j] * f[j]; }
  #pragma unroll
  for (int o = 32; o > 0; o >>= 1) s += __shfl_xor(s, o);
  if (lane == 0) wred[4 + wave] = s;
  __syncthreads();
  float rstd = rsqrtf((wred[4] + wred[5] + wred[6] + wred[7]) / 1024.0f + 1e-5f);
  float4 gv4 = *(const float4*)(g + t * 4);
  float4 bv4 = *(const float4*)(b + t * 4);
  float4 ov;
  ov.x = f[0] * rstd * gv4.x + bv4.x;
  ov.y = f[1] * rstd * gv4.y + bv4.y;
  ov.z = f[2] * rstd * gv4.z + bv4.z;
  ov.w = f[3] * rstd * gv4.w + bv4.w;
  *(float4*)(out + base) = ov;
}

// ---------------------------------------------------------------------------
// launch
// ---------------------------------------------------------------------------
extern "C" void kernel_launch(void* const* d_in, const int* in_sizes, int n_in,
                              void* d_out, int out_size, void* d_ws, size_t ws_size,
                              hipStream_t stream) {
  const float* qh   = (const float*)d_in[0];
  const float* memk = (const float*)d_in[1];
  const float* sel  = (const float*)d_in[2];
  const float* qp_w = (const float*)d_in[3];
  const float* qp_b = (const float*)d_in[4];
  const float* inw  = (const float*)d_in[5];
  const float* inb  = (const float*)d_in[6];
  const float* outw = (const float*)d_in[7];
  const float* outb = (const float*)d_in[8];
  const float* gw   = (const float*)d_in[9];
  const float* gb   = (const float*)d_in[10];
  const float* w1   = (const float*)d_in[11];
  const float* b1   = (const float*)d_in[12];
  const float* lng  = (const float*)d_in[13];
  const float* lnb  = (const float*)d_in[14];
  const float* w2   = (const float*)d_in[15];
  const float* b2   = (const float*)d_in[16];
  const float* ln1g = (const float*)d_in[17];
  const float* ln1b = (const float*)d_in[18];
  const float* ln2g = (const float*)d_in[19];
  const float* ln2b = (const float*)d_in[20];
  float* out = (float*)d_out;
  char* ws = (char*)d_ws;

  // workspace arena (bytes); lifetimes: t1 overlays S/P, integ overlays qh_bf
  const size_t IDX_O   = 0;          // 512*4
  const size_t BCQ_O   = 2048;       // 256*4
  const size_t WCB_O   = 3072;       // 256*1024*2   = 524288
  const size_t KMAT_O  = 527360;     // 512*256*2    = 262144
  const size_t VT_O    = 789504;     // 4*64*512*2   = 262144
  const size_t OUTWB_O = 1051648;    // 65536*2      = 131072
  const size_t GATEW_O = 1182720;    // 1310720*2    = 2621440
  const size_t INTW1_O = 3804160;    // 2621440*2    = 5242880
  const size_t INTW2_O = 9047040;    // 2097152*2    = 4194304
  const size_t QHB_O   = 13241344;   // 16777216*2   = 33554432  (later: integrated)
  const size_t QB_O    = 46795776;   // 16384*256*2  = 8388608
  const size_t SB_O    = 55184384;   // 4*16384*512*2= 67108864  (later: t1)
  const size_t CTX_O   = 122293248;  // 8388608
  const size_t ATTN_O  = 130681856;  // 8388608
  const size_t GATE_O  = 139070464;  // 33554432
  // total = 172,624,896 bytes

  int*    idxb   = (int*)(ws + IDX_O);
  float*  bcq    = (float*)(ws + BCQ_O);
  __bf16* wcb    = (__bf16*)(ws + WCB_O);
  __bf16* kmat   = (__bf16*)(ws + KMAT_O);
  __bf16* vt     = (__bf16*)(ws + VT_O);
  __bf16* outwb  = (__bf16*)(ws + OUTWB_O);
  __bf16* gatewb = (__bf16*)(ws + GATEW_O);
  __bf16* intw1b = (__bf16*)(ws + INTW1_O);
  __bf16* intw2b = (__bf16*)(ws + INTW2_O);
  __bf16* qhb    = (__bf16*)(ws + QHB_O);
  __bf16* integb = (__bf16*)(ws + QHB_O);   // reuse: qh_bf dead after t1 GEMM
  __bf16* qb     = (__bf16*)(ws + QB_O);
  __bf16* sb     = (__bf16*)(ws + SB_O);
  __bf16* t1b    = (__bf16*)(ws + SB_O);    // reuse: S/P dead after ctx GEMM
  __bf16* ctxb   = (__bf16*)(ws + CTX_O);
  __bf16* attnb  = (__bf16*)(ws + ATTN_O);
  __bf16* gateb  = (__bf16*)(ws + GATE_O);

  // 1) convert qh + big weights to bf16
  cvt_kernel<<<22336, 256, 0, stream>>>(qh, outw, gw, w1, w2,
                                        qhb, outwb, gatewb, intw1b, intw2b);
  // 2) top-512
  topk_kernel<<<1, 256, 0, stream>>>(sel, idxb);
  // 3) folded Q-projection weight (with 1/8 softmax scale)
  wc_build<<<256, 256, 0, stream>>>(qp_w, qp_b, inw, inb, wcb, bcq);
  // 4) gather + LN + K,Vt
  kv_build<<<512, 256, 0, stream>>>(idxb, memk, inw, inb, ln1g, ln1b, kmat, vt);
  // 5) Q = qh_bf @ Wc^T + bcq   [16384 x 256], K=1024
  gemm_kernel<128, 128, 0><<<dim3(128, 2, 1), 256, 0, stream>>>(
      qhb, 1024, 1024, (const __bf16*)nullptr, 0, wcb, 1024, bcq, qb, 256, 1024, 0, 0, 0);
  // 6) S_h = Q_h @ K_h^T  (scale folded), per head  [16384 x 512], K=64
  gemm_kernel<128, 128, 1><<<dim3(128, 4, 4), 256, 0, stream>>>(
      qb, 256, 64, (const __bf16*)nullptr, 0, kmat, 256, (const float*)nullptr,
      sb, 512, 64, 64, 64, (long)16384 * 512);
  // 7) softmax in place (65536 rows of 512)
  softmax_kernel<<<16384, 256, 0, stream>>>(sb);
  // 8) ctx_h = P_h @ Vt_h^T  [16384 x 64], K=512
  gemm_kernel<128, 64, 1><<<dim3(128, 1, 4), 256, 0, stream>>>(
      sb, 512, 512, (const __bf16*)nullptr, 0, vt, 512, (const float*)nullptr,
      ctxb, 256, 512, (long)16384 * 512, (long)64 * 512, 64);
  // 9) attn_out = ctx @ out_w^T + out_b  [16384 x 256], K=256
  gemm_kernel<128, 128, 0><<<dim3(128, 2, 1), 256, 0, stream>>>(
      ctxb, 256, 256, (const __bf16*)nullptr, 0, outwb, 256, outb, attnb, 256, 256, 0, 0, 0);
  // 10) gate = sigmoid([qh,attn] @ gate_w^T + gate_b)  [16384 x 1024], K=1280
  gemm_kernel<128, 128, 2><<<dim3(128, 8, 1), 256, 0, stream>>>(
      qhb, 1024, 1024, attnb, 256, gatewb, 1280, gb, gateb, 1024, 1280, 0, 0, 0);
  // 11) t1 = [qh,attn] @ int_w1^T + int_b1  [16384 x 2048], K=1280
  gemm_kernel<128, 128, 0><<<dim3(128, 16, 1), 256, 0, stream>>>(
      qhb, 1024, 1024, attnb, 256, intw1b, 1280, b1, t1b, 2048, 1280, 0, 0, 0);
  // 12) h = gelu(LN(t1)) in place
  ln_gelu_kernel<<<16384, 256, 0, stream>>>(t1b, lng, lnb);
  // 13) integrated = h @ int_w2^T + int_b2  [16384 x 1024], K=2048
  gemm_kernel<128, 128, 0><<<dim3(128, 8, 1), 256, 0, stream>>>(
      t1b, 2048, 2048, (const __bf16*)nullptr, 0, intw2b, 2048, b2, integb, 1024, 2048, 0, 0, 0);
  // 14) out = LN(qh + gate*integrated; ln2)
  final_kernel<<<16384, 256, 0, stream>>>(qh, gateb, integb, ln2g, ln2b, out);
}